// Round 1
// baseline (671.488 us; speedup 1.0000x reference)
//
#include <hip/hip_runtime.h>
#include <hip/hip_bf16.h>
#include <stdint.h>

#define N_NODES 50000
#define N_EDGES 800000
#define NH 8
#define VD 320

// ---- float <-> orderable uint (for atomicMax on signed floats) ----
__device__ __forceinline__ unsigned mapf(float f) {
    unsigned b = __float_as_uint(f);
    return ((int)b >= 0) ? (b | 0x80000000u) : ~b;
}
__device__ __forceinline__ float unmapf(unsigned u) {
    unsigned b = (u & 0x80000000u) ? (u ^ 0x80000000u) : ~u;
    return __uint_as_float(b);
}

// ---- K0: init stats buffers ----
__global__ void k_init(float* __restrict__ s, unsigned* __restrict__ m_u,
                       unsigned* __restrict__ cnt) {
    int i = blockIdx.x * blockDim.x + threadIdx.x;
    int stride = gridDim.x * blockDim.x;
    for (int j = i; j < N_NODES * NH; j += stride) { s[j] = 0.0f; m_u[j] = 0u; }
    for (int j = i; j < N_NODES; j += stride) cnt[j] = 0u;
}

// ---- K1: per-(edge,head) running max + per-edge degree histogram ----
__global__ __launch_bounds__(256) void k_max_hist(
        const float* __restrict__ ew, const float* __restrict__ cutoff,
        const int* __restrict__ dst, unsigned* __restrict__ m_u,
        unsigned* __restrict__ cnt) {
    int i = blockIdx.x * 256 + threadIdx.x;
    if (i >= N_EDGES * NH) return;
    int e = i >> 3, h = i & 7;
    int d = dst[e];
    float w = cutoff[e] * ew[i];
    atomicMax(&m_u[d * NH + h], mapf(w));
    if (h == 0) atomicAdd(&cnt[d], 1u);
}

// ---- K2: single-block exclusive scan of degree -> rowstart, cursor ----
__global__ __launch_bounds__(1024) void k_scan(const unsigned* __restrict__ cnt,
                                               unsigned* __restrict__ rowstart,
                                               unsigned* __restrict__ cursor) {
    __shared__ unsigned part[1024];
    const int CH = (N_NODES + 1023) / 1024;  // 49
    int t = threadIdx.x;
    int lo = t * CH, hi = lo + CH < N_NODES ? lo + CH : N_NODES;
    unsigned sum = 0;
    for (int i = lo; i < hi; ++i) sum += cnt[i];
    part[t] = sum;
    __syncthreads();
    for (int off = 1; off < 1024; off <<= 1) {
        unsigned v = part[t];
        unsigned add = (t >= off) ? part[t - off] : 0u;
        __syncthreads();
        part[t] = v + add;
        __syncthreads();
    }
    unsigned base = (t == 0) ? 0u : part[t - 1];
    for (int i = lo; i < hi; ++i) {
        rowstart[i] = base;
        cursor[i] = base;
        base += cnt[i];
    }
    if (t == 1023) rowstart[N_NODES] = part[1023];
}

// ---- K3: exp-sum accumulation + CSR scatter of edge ids ----
__global__ __launch_bounds__(256) void k_scatter_sum(
        const float* __restrict__ ew, const float* __restrict__ cutoff,
        const int* __restrict__ dst, const unsigned* __restrict__ m_u,
        float* __restrict__ s, unsigned* __restrict__ cursor,
        unsigned* __restrict__ eid) {
    int i = blockIdx.x * 256 + threadIdx.x;
    if (i >= N_EDGES * NH) return;
    int e = i >> 3, h = i & 7;
    int d = dst[e];
    float w = cutoff[e] * ew[i];
    float m = unmapf(m_u[d * NH + h]);
    atomicAdd(&s[d * NH + h], __expf(w - m));
    if (h == 0) {
        unsigned pos = atomicAdd(&cursor[d], 1u);
        eid[pos] = (unsigned)e;
    }
}

// ---- K4: attention coefficients a[e,h] ----
__global__ __launch_bounds__(256) void k_coef(
        const float* __restrict__ ew, const float* __restrict__ cutoff,
        const int* __restrict__ dst, const unsigned* __restrict__ m_u,
        const float* __restrict__ s, float* __restrict__ a) {
    int i = blockIdx.x * 256 + threadIdx.x;
    if (i >= N_EDGES * NH) return;
    int e = i >> 3, h = i & 7;
    int d = dst[e];
    float w = cutoff[e] * ew[i];
    float m = unmapf(m_u[d * NH + h]);
    a[i] = __expf(w - m) / s[d * NH + h];
}

// ---- K5: gather-aggregate. One block per node, one thread per column ----
__global__ __launch_bounds__(320) void k_gather(
        const float* __restrict__ a, const float* __restrict__ value,
        const unsigned* __restrict__ rowstart, const unsigned* __restrict__ eid,
        float* __restrict__ out) {
    int n = blockIdx.x;
    int c = threadIdx.x;
    // column -> head: block0 (cols 0..127) 16/head, block1 (cols 128..319) 24/head
    int h = (c < 128) ? (c >> 4) : ((c - 128) / 24);
    unsigned k0 = rowstart[n], k1 = rowstart[n + 1];
    float acc = 0.0f;
    for (unsigned k = k0; k < k1; ++k) {
        unsigned e = eid[k];
        acc += a[e * NH + h] * value[(size_t)e * VD + c];
    }
    out[(size_t)n * VD + c] = acc;
}

extern "C" void kernel_launch(void* const* d_in, const int* in_sizes, int n_in,
                              void* d_out, int out_size, void* d_ws, size_t ws_size,
                              hipStream_t stream) {
    const float* value  = (const float*)d_in[0];
    const float* ew     = (const float*)d_in[1];
    const float* cutoff = (const float*)d_in[2];
    const int*   eidx   = (const int*)d_in[3];
    const int*   dst    = eidx + N_EDGES;  // edge_index[1]
    float* out = (float*)d_out;

    // workspace layout (all 16B-aligned sizes)
    char* ws = (char*)d_ws;
    unsigned* m_u     = (unsigned*)ws; ws += (size_t)N_NODES * NH * 4;     // 1.6 MB
    float*    s       = (float*)ws;    ws += (size_t)N_NODES * NH * 4;     // 1.6 MB
    float*    a       = (float*)ws;    ws += (size_t)N_EDGES * NH * 4;     // 25.6 MB
    unsigned* cnt     = (unsigned*)ws; ws += (size_t)((N_NODES + 3) & ~3) * 4;
    unsigned* rowstart= (unsigned*)ws; ws += (size_t)((N_NODES + 1 + 3) & ~3) * 4;
    unsigned* cursor  = (unsigned*)ws; ws += (size_t)((N_NODES + 3) & ~3) * 4;
    unsigned* eid     = (unsigned*)ws; ws += (size_t)N_EDGES * 4;          // 3.2 MB

    const int g8 = (N_EDGES * NH + 255) / 256;  // 25000 blocks

    k_init<<<512, 256, 0, stream>>>(s, m_u, cnt);
    k_max_hist<<<g8, 256, 0, stream>>>(ew, cutoff, dst, m_u, cnt);
    k_scan<<<1, 1024, 0, stream>>>(cnt, rowstart, cursor);
    k_scatter_sum<<<g8, 256, 0, stream>>>(ew, cutoff, dst, m_u, s, cursor, eid);
    k_coef<<<g8, 256, 0, stream>>>(ew, cutoff, dst, m_u, s, a);
    k_gather<<<N_NODES, VD, 0, stream>>>(a, value, rowstart, eid, out);
}

// Round 2
// 428.039 us; speedup vs baseline: 1.5688x; 1.5688x over previous
//
#include <hip/hip_runtime.h>
#include <hip/hip_bf16.h>
#include <stdint.h>

#define N_NODES 50000
#define N_EDGES 800000
#define NH 8
#define VD 320

// ---- K0: zero stats ----
__global__ void k_init(float* __restrict__ s, unsigned* __restrict__ cnt,
                       unsigned* __restrict__ total) {
    int i = blockIdx.x * blockDim.x + threadIdx.x;
    int stride = gridDim.x * blockDim.x;
    for (int j = i; j < N_NODES * NH; j += stride) s[j] = 0.0f;
    for (int j = i; j < N_NODES; j += stride) cnt[j] = 0u;
    if (i == 0) *total = 0u;
}

// ---- K1: fused exp + denom-sum + degree histogram + store exp(w) ----
// softmax is shift-invariant; |w| = |cutoff*ew| <= ~6 so exp() is safe
// without the max-subtraction pass.
__global__ __launch_bounds__(256) void k_exp_sum(
        const float* __restrict__ ew, const float* __restrict__ cutoff,
        const int* __restrict__ dst, float* __restrict__ s,
        unsigned* __restrict__ cnt, float* __restrict__ expw) {
    int i = blockIdx.x * 256 + threadIdx.x;
    if (i >= N_EDGES * NH) return;
    int e = i >> 3, h = i & 7;
    int d = dst[e];
    float p = __expf(cutoff[e] * ew[i]);
    expw[i] = p;
    atomicAdd(&s[d * NH + h], p);
    if (h == 0) atomicAdd(&cnt[d], 1u);
}

// ---- K2: range allocation (unordered CSR) via wave-aggregated atomicAdd ----
__global__ __launch_bounds__(256) void k_ranges(
        const unsigned* __restrict__ cnt, unsigned* __restrict__ rowstart,
        unsigned* __restrict__ cursor, unsigned* __restrict__ total) {
    int i = blockIdx.x * 256 + threadIdx.x;
    int lane = threadIdx.x & 63;
    unsigned c = (i < N_NODES) ? cnt[i] : 0u;
    // wave-64 inclusive scan
    unsigned incl = c;
    #pragma unroll
    for (int off = 1; off < 64; off <<= 1) {
        unsigned v = __shfl_up(incl, off, 64);
        if (lane >= off) incl += v;
    }
    unsigned wave_total = __shfl(incl, 63, 64);
    unsigned base = 0;
    if (lane == 63) base = atomicAdd(total, wave_total);
    base = __shfl(base, 63, 64);
    if (i < N_NODES) {
        unsigned st = base + incl - c;
        rowstart[i] = st;
        cursor[i] = st;
    }
}

// ---- K3: scatter edge ids into per-node slots ----
__global__ __launch_bounds__(256) void k_scatter(
        const int* __restrict__ dst, unsigned* __restrict__ cursor,
        unsigned* __restrict__ eid) {
    int e = blockIdx.x * 256 + threadIdx.x;
    if (e >= N_EDGES) return;
    int d = dst[e];
    unsigned pos = atomicAdd(&cursor[d], 1u);
    eid[pos] = (unsigned)e;
}

// ---- K4: gather-aggregate ----
// Block = one node. 320 threads = 80 column-groups (float4) x 4 edge slots.
// 4 independent load chains per thread-column -> BW-bound, 16B/lane loads.
__global__ __launch_bounds__(320) void k_gather(
        const float* __restrict__ expw, const float* __restrict__ value,
        const unsigned* __restrict__ rowstart, const unsigned* __restrict__ cnt,
        const float* __restrict__ s, const unsigned* __restrict__ eid,
        float* __restrict__ out) {
    int n = blockIdx.x;
    int t = threadIdx.x;
    int cg = t % 80;     // column group: cols [4cg, 4cg+3]
    int slot = t / 80;   // edge slot 0..3
    int c = cg * 4;
    // 4-col group never crosses a head boundary (16%4==0, 24%4==0)
    int h = (c < 128) ? (c >> 4) : ((c - 128) / 24);
    unsigned k0 = rowstart[n];
    unsigned deg = cnt[n];
    float inv = 1.0f / s[n * NH + h];  // inf if deg==0, but then loop is skipped
    float ax = 0.f, ay = 0.f, az = 0.f, aw = 0.f;
    for (unsigned k = slot; k < deg; k += 4) {
        unsigned e = eid[k0 + k];
        float aa = expw[e * NH + h] * inv;
        const float4 v = *reinterpret_cast<const float4*>(value + (size_t)e * VD + c);
        ax += aa * v.x; ay += aa * v.y; az += aa * v.z; aw += aa * v.w;
    }
    __shared__ float4 red[4][80];
    if (slot > 0) red[slot][cg] = make_float4(ax, ay, az, aw);
    __syncthreads();
    if (slot == 0) {
        float4 r1 = red[1][cg], r2 = red[2][cg], r3 = red[3][cg];
        ax += r1.x + r2.x + r3.x;
        ay += r1.y + r2.y + r3.y;
        az += r1.z + r2.z + r3.z;
        aw += r1.w + r2.w + r3.w;
        *reinterpret_cast<float4*>(out + (size_t)n * VD + c) = make_float4(ax, ay, az, aw);
    }
}

extern "C" void kernel_launch(void* const* d_in, const int* in_sizes, int n_in,
                              void* d_out, int out_size, void* d_ws, size_t ws_size,
                              hipStream_t stream) {
    const float* value  = (const float*)d_in[0];
    const float* ew     = (const float*)d_in[1];
    const float* cutoff = (const float*)d_in[2];
    const int*   eidx   = (const int*)d_in[3];
    const int*   dst    = eidx + N_EDGES;  // edge_index[1]
    float* out = (float*)d_out;

    char* ws = (char*)d_ws;
    float*    s        = (float*)ws;    ws += (size_t)N_NODES * NH * 4;   // 1.6 MB
    float*    expw     = (float*)ws;    ws += (size_t)N_EDGES * NH * 4;   // 25.6 MB
    unsigned* cnt      = (unsigned*)ws; ws += (size_t)((N_NODES + 3) & ~3) * 4;
    unsigned* rowstart = (unsigned*)ws; ws += (size_t)((N_NODES + 3) & ~3) * 4;
    unsigned* cursor   = (unsigned*)ws; ws += (size_t)((N_NODES + 3) & ~3) * 4;
    unsigned* eid      = (unsigned*)ws; ws += (size_t)N_EDGES * 4;        // 3.2 MB
    unsigned* total    = (unsigned*)ws; ws += 16;

    const int g8 = (N_EDGES * NH + 255) / 256;   // 25000
    const int gE = (N_EDGES + 255) / 256;        // 3125
    const int gN = (N_NODES + 255) / 256;        // 196

    k_init<<<512, 256, 0, stream>>>(s, cnt, total);
    k_exp_sum<<<g8, 256, 0, stream>>>(ew, cutoff, dst, s, cnt, expw);
    k_ranges<<<gN, 256, 0, stream>>>(cnt, rowstart, cursor, total);
    k_scatter<<<gE, 256, 0, stream>>>(dst, cursor, eid);
    k_gather<<<N_NODES, 320, 0, stream>>>(expw, value, rowstart, cnt, s, eid, out);
}

// Round 4
// 345.442 us; speedup vs baseline: 1.9439x; 1.2391x over previous
//
#include <hip/hip_runtime.h>
#include <hip/hip_bf16.h>
#include <stdint.h>

#define N_NODES 50000
#define N_EDGES 800000
#define NH 8
#define VD 320

typedef float f32x4 __attribute__((ext_vector_type(4)));

// ---- K0: zero degree counts + global cursor ----
__global__ void k_init(unsigned* __restrict__ cnt, unsigned* __restrict__ total) {
    int i = blockIdx.x * blockDim.x + threadIdx.x;
    int stride = gridDim.x * blockDim.x;
    for (int j = i; j < N_NODES; j += stride) cnt[j] = 0u;
    if (i == 0) *total = 0u;
}

// ---- K1: one thread per edge: exp(cutoff*ew) for all 8 heads + degree histogram ----
// softmax is shift-invariant and |cutoff*ew| <= ~6, so no max-subtraction needed
// (validated in R1/R2: absmax 0.0078 << 0.078 threshold).
__global__ __launch_bounds__(256) void k_exp(
        const float* __restrict__ ew, const float* __restrict__ cutoff,
        const int* __restrict__ dst, unsigned* __restrict__ cnt,
        float* __restrict__ expw) {
    int e = blockIdx.x * 256 + threadIdx.x;
    if (e >= N_EDGES) return;
    float cw = cutoff[e];
    const f32x4* ewv = reinterpret_cast<const f32x4*>(ew + (size_t)e * NH);
    f32x4 w0 = ewv[0], w1 = ewv[1];
    f32x4 p0, p1;
    p0.x = __expf(cw * w0.x); p0.y = __expf(cw * w0.y);
    p0.z = __expf(cw * w0.z); p0.w = __expf(cw * w0.w);
    p1.x = __expf(cw * w1.x); p1.y = __expf(cw * w1.y);
    p1.z = __expf(cw * w1.z); p1.w = __expf(cw * w1.w);
    f32x4* ov = reinterpret_cast<f32x4*>(expw + (size_t)e * NH);
    ov[0] = p0; ov[1] = p1;
    atomicAdd(&cnt[dst[e]], 1u);
}

// ---- K2: unordered CSR range allocation (wave-scan + one atomic per wave) ----
__global__ __launch_bounds__(256) void k_ranges(
        const unsigned* __restrict__ cnt, unsigned* __restrict__ rowstart,
        unsigned* __restrict__ cursor, unsigned* __restrict__ total) {
    int i = blockIdx.x * 256 + threadIdx.x;
    int lane = threadIdx.x & 63;
    unsigned c = (i < N_NODES) ? cnt[i] : 0u;
    unsigned incl = c;
    #pragma unroll
    for (int off = 1; off < 64; off <<= 1) {
        unsigned v = __shfl_up(incl, off, 64);
        if (lane >= off) incl += v;
    }
    unsigned wave_total = __shfl(incl, 63, 64);
    unsigned base = 0;
    if (lane == 63) base = atomicAdd(total, wave_total);
    base = __shfl(base, 63, 64);
    if (i < N_NODES) {
        unsigned st = base + incl - c;
        rowstart[i] = st;
        cursor[i] = st;
    }
}

// ---- K3: scatter edge ids into per-node slots ----
__global__ __launch_bounds__(256) void k_scatter(
        const int* __restrict__ dst, unsigned* __restrict__ cursor,
        unsigned* __restrict__ eid) {
    int e = blockIdx.x * 256 + threadIdx.x;
    if (e >= N_EDGES) return;
    unsigned pos = atomicAdd(&cursor[dst[e]], 1u);
    eid[pos] = (unsigned)e;
}

// ---- K4: persistent gather-aggregate ----
// Block = 320 threads = 4 nodes x 80 float4-column-groups; grid-stride over nodes.
// Each thread loops all deg edges of its node with unroll-4 (4 independent
// eid->value chains), accumulates both Sum(expw*v) and the softmax denominator
// Sum(expw) inline, and scales once at the end. No LDS, no syncthreads,
// no s[] array, no atomics.
__global__ __launch_bounds__(320) void k_gather(
        const float* __restrict__ expw, const float* __restrict__ value,
        const unsigned* __restrict__ rowstart, const unsigned* __restrict__ cnt,
        const unsigned* __restrict__ eid, float* __restrict__ out) {
    int t = threadIdx.x;
    int cg = t % 80;    // column group: cols [4cg, 4cg+3]
    int ns = t / 80;    // node sub-slot 0..3
    int c = cg * 4;
    // 4-col group never crosses a head boundary (16%4==0, 24%4==0)
    int h = (c < 128) ? (c >> 4) : ((c - 128) / 24);
    for (int n = blockIdx.x * 4 + ns; n < N_NODES; n += gridDim.x * 4) {
        unsigned k0 = rowstart[n];
        unsigned deg = cnt[n];
        float sx = 0.f, sy = 0.f, sz = 0.f, sw = 0.f, se = 0.f;
        unsigned k = 0;
        for (; k + 4 <= deg; k += 4) {
            unsigned e0 = eid[k0 + k],     e1 = eid[k0 + k + 1];
            unsigned e2 = eid[k0 + k + 2], e3 = eid[k0 + k + 3];
            float a0 = expw[e0 * NH + h], a1 = expw[e1 * NH + h];
            float a2 = expw[e2 * NH + h], a3 = expw[e3 * NH + h];
            f32x4 v0 = __builtin_nontemporal_load(
                reinterpret_cast<const f32x4*>(value + (size_t)(e0 * VD + c)));
            f32x4 v1 = __builtin_nontemporal_load(
                reinterpret_cast<const f32x4*>(value + (size_t)(e1 * VD + c)));
            f32x4 v2 = __builtin_nontemporal_load(
                reinterpret_cast<const f32x4*>(value + (size_t)(e2 * VD + c)));
            f32x4 v3 = __builtin_nontemporal_load(
                reinterpret_cast<const f32x4*>(value + (size_t)(e3 * VD + c)));
            se += (a0 + a1) + (a2 + a3);
            sx += a0 * v0.x + a1 * v1.x + a2 * v2.x + a3 * v3.x;
            sy += a0 * v0.y + a1 * v1.y + a2 * v2.y + a3 * v3.y;
            sz += a0 * v0.z + a1 * v1.z + a2 * v2.z + a3 * v3.z;
            sw += a0 * v0.w + a1 * v1.w + a2 * v2.w + a3 * v3.w;
        }
        for (; k < deg; ++k) {
            unsigned e = eid[k0 + k];
            float a = expw[e * NH + h];
            f32x4 v = __builtin_nontemporal_load(
                reinterpret_cast<const f32x4*>(value + (size_t)(e * VD + c)));
            se += a;
            sx += a * v.x; sy += a * v.y; sz += a * v.z; sw += a * v.w;
        }
        float scale = (deg > 0) ? 1.0f / se : 0.0f;
        f32x4 r;
        r.x = sx * scale; r.y = sy * scale; r.z = sz * scale; r.w = sw * scale;
        __builtin_nontemporal_store(r,
            reinterpret_cast<f32x4*>(out + (size_t)n * VD + c));
    }
}

extern "C" void kernel_launch(void* const* d_in, const int* in_sizes, int n_in,
                              void* d_out, int out_size, void* d_ws, size_t ws_size,
                              hipStream_t stream) {
    const float* value  = (const float*)d_in[0];
    const float* ew     = (const float*)d_in[1];
    const float* cutoff = (const float*)d_in[2];
    const int*   eidx   = (const int*)d_in[3];
    const int*   dst    = eidx + N_EDGES;  // edge_index[1]
    float* out = (float*)d_out;

    char* ws = (char*)d_ws;
    float*    expw     = (float*)ws;    ws += (size_t)N_EDGES * NH * 4;   // 25.6 MB
    unsigned* cnt      = (unsigned*)ws; ws += (size_t)((N_NODES + 3) & ~3) * 4;
    unsigned* rowstart = (unsigned*)ws; ws += (size_t)((N_NODES + 3) & ~3) * 4;
    unsigned* cursor   = (unsigned*)ws; ws += (size_t)((N_NODES + 3) & ~3) * 4;
    unsigned* eid      = (unsigned*)ws; ws += (size_t)N_EDGES * 4;        // 3.2 MB
    unsigned* total    = (unsigned*)ws; ws += 16;

    const int gE = (N_EDGES + 255) / 256;   // 3125
    const int gN = (N_NODES + 255) / 256;   // 196

    k_init<<<196, 256, 0, stream>>>(cnt, total);
    k_exp<<<gE, 256, 0, stream>>>(ew, cutoff, dst, cnt, expw);
    k_ranges<<<gN, 256, 0, stream>>>(cnt, rowstart, cursor, total);
    k_scatter<<<gE, 256, 0, stream>>>(dst, cursor, eid);
    k_gather<<<2048, 320, 0, stream>>>(expw, value, rowstart, cnt, eid, out);
}

// Round 5
// 340.118 us; speedup vs baseline: 1.9743x; 1.0157x over previous
//
#include <hip/hip_runtime.h>
#include <hip/hip_bf16.h>
#include <stdint.h>

#define N_NODES 50000
#define N_EDGES 800000
#define NH 8
#define VD 320

typedef float f32x4 __attribute__((ext_vector_type(4)));

// ---- K0: zero degree counts + global cursor ----
__global__ void k_init(unsigned* __restrict__ cnt, unsigned* __restrict__ total) {
    int i = blockIdx.x * blockDim.x + threadIdx.x;
    int stride = gridDim.x * blockDim.x;
    for (int j = i; j < N_NODES; j += stride) cnt[j] = 0u;
    if (i == 0) *total = 0u;
}

// ---- K1: degree histogram ----
__global__ __launch_bounds__(256) void k_hist(
        const int* __restrict__ dst, unsigned* __restrict__ cnt) {
    int e = blockIdx.x * 256 + threadIdx.x;
    if (e >= N_EDGES) return;
    atomicAdd(&cnt[dst[e]], 1u);
}

// ---- K2: unordered CSR range allocation (wave-scan + one atomic per wave) ----
__global__ __launch_bounds__(256) void k_ranges(
        const unsigned* __restrict__ cnt, unsigned* __restrict__ rowstart,
        unsigned* __restrict__ cursor, unsigned* __restrict__ total) {
    int i = blockIdx.x * 256 + threadIdx.x;
    int lane = threadIdx.x & 63;
    unsigned c = (i < N_NODES) ? cnt[i] : 0u;
    unsigned incl = c;
    #pragma unroll
    for (int off = 1; off < 64; off <<= 1) {
        unsigned v = __shfl_up(incl, off, 64);
        if (lane >= off) incl += v;
    }
    unsigned wave_total = __shfl(incl, 63, 64);
    unsigned base = 0;
    if (lane == 63) base = atomicAdd(total, wave_total);
    base = __shfl(base, 63, 64);
    if (i < N_NODES) {
        unsigned st = base + incl - c;
        rowstart[i] = st;
        cursor[i] = st;
    }
}

// ---- K3: scatter packed (edge id, cutoff) into per-node CSR slots ----
__global__ __launch_bounds__(256) void k_scatter(
        const int* __restrict__ dst, const float* __restrict__ cutoff,
        unsigned* __restrict__ cursor, uint2* __restrict__ csr) {
    int e = blockIdx.x * 256 + threadIdx.x;
    if (e >= N_EDGES) return;
    unsigned pos = atomicAdd(&cursor[dst[e]], 1u);
    uint2 p; p.x = (unsigned)e; p.y = __float_as_uint(cutoff[e]);
    csr[pos] = p;
}

// ---- K4: wave-per-node gather ----
// One wave64 owns a node. Lane l handles cols [4l,4l+3]; lanes 0-15 additionally
// handle cols [256+4l .. 256+4l+3] -> the full 1280B value row is requested by
// one wave back-to-back (one contiguous DRAM burst per edge). Edge list chunk
// (64 entries) is register-cached and broadcast via shfl. exp() computed on the
// fly; softmax denominator accumulated per-lane (identical across lanes of the
// same head), applied once at the end.
__global__ __launch_bounds__(256) void k_gather(
        const float* __restrict__ ew, const float* __restrict__ value,
        const unsigned* __restrict__ rowstart, const unsigned* __restrict__ cnt,
        const uint2* __restrict__ csr, float* __restrict__ out) {
    int lane = threadIdx.x & 63;
    int wslot = blockIdx.x * 4 + (threadIdx.x >> 6);
    int nslots = gridDim.x * 4;
    int c = lane * 4;
    int h = (c < 128) ? (c >> 4) : ((c - 128) / 24);
    int c2 = 256 + c;                 // secondary cols, lanes 0-15 only
    int h2 = (c2 - 128) / 24;
    bool sec = lane < 16;
    for (int n = wslot; n < N_NODES; n += nslots) {
        unsigned k0 = rowstart[n];
        unsigned deg = cnt[n];
        f32x4 acc = {0.f, 0.f, 0.f, 0.f}, acc2 = {0.f, 0.f, 0.f, 0.f};
        float se = 0.f, se2 = 0.f;
        for (unsigned base = 0; base < deg; base += 64) {
            unsigned m = deg - base; if (m > 64u) m = 64u;
            unsigned pe = 0u, pc = 0u;
            if (lane < (int)m) {
                uint2 p = csr[k0 + base + lane];
                pe = p.x; pc = p.y;
            }
            #pragma unroll 2
            for (unsigned j = 0; j < m; ++j) {
                unsigned e = (unsigned)__shfl((int)pe, (int)j, 64);
                float cu = __uint_as_float(__shfl((int)pc, (int)j, 64));
                const float* vrow = value + (size_t)e * VD;
                float w = ew[(size_t)e * NH + h];
                f32x4 v = __builtin_nontemporal_load(
                    reinterpret_cast<const f32x4*>(vrow + c));
                float a = __expf(cu * w);
                se += a;
                acc.x += a * v.x; acc.y += a * v.y;
                acc.z += a * v.z; acc.w += a * v.w;
                if (sec) {
                    float w2 = ew[(size_t)e * NH + h2];
                    f32x4 v2 = __builtin_nontemporal_load(
                        reinterpret_cast<const f32x4*>(vrow + c2));
                    float a2 = __expf(cu * w2);
                    se2 += a2;
                    acc2.x += a2 * v2.x; acc2.y += a2 * v2.y;
                    acc2.z += a2 * v2.z; acc2.w += a2 * v2.w;
                }
            }
        }
        float sc = (deg > 0) ? 1.0f / se : 0.0f;
        f32x4 r; r.x = acc.x * sc; r.y = acc.y * sc;
        r.z = acc.z * sc; r.w = acc.w * sc;
        __builtin_nontemporal_store(r,
            reinterpret_cast<f32x4*>(out + (size_t)n * VD + c));
        if (sec) {
            float sc2 = (deg > 0) ? 1.0f / se2 : 0.0f;
            f32x4 r2; r2.x = acc2.x * sc2; r2.y = acc2.y * sc2;
            r2.z = acc2.z * sc2; r2.w = acc2.w * sc2;
            __builtin_nontemporal_store(r2,
                reinterpret_cast<f32x4*>(out + (size_t)n * VD + c2));
        }
    }
}

extern "C" void kernel_launch(void* const* d_in, const int* in_sizes, int n_in,
                              void* d_out, int out_size, void* d_ws, size_t ws_size,
                              hipStream_t stream) {
    const float* value  = (const float*)d_in[0];
    const float* ew     = (const float*)d_in[1];
    const float* cutoff = (const float*)d_in[2];
    const int*   eidx   = (const int*)d_in[3];
    const int*   dst    = eidx + N_EDGES;  // edge_index[1]
    float* out = (float*)d_out;

    char* ws = (char*)d_ws;
    unsigned* cnt      = (unsigned*)ws; ws += (size_t)((N_NODES + 3) & ~3) * 4;
    unsigned* rowstart = (unsigned*)ws; ws += (size_t)((N_NODES + 3) & ~3) * 4;
    unsigned* cursor   = (unsigned*)ws; ws += (size_t)((N_NODES + 3) & ~3) * 4;
    unsigned* total    = (unsigned*)ws; ws += 16;
    uint2*    csr      = (uint2*)ws;    ws += (size_t)N_EDGES * 8;   // 6.4 MB

    const int gE = (N_EDGES + 255) / 256;   // 3125
    const int gN = (N_NODES + 255) / 256;   // 196

    k_init<<<196, 256, 0, stream>>>(cnt, total);
    k_hist<<<gE, 256, 0, stream>>>(dst, cnt);
    k_ranges<<<gN, 256, 0, stream>>>(cnt, rowstart, cursor, total);
    k_scatter<<<gE, 256, 0, stream>>>(dst, cutoff, cursor, csr);
    k_gather<<<2048, 256, 0, stream>>>(ew, value, rowstart, cnt, csr, out);
}

// Round 6
// 323.162 us; speedup vs baseline: 2.0779x; 1.0525x over previous
//
#include <hip/hip_runtime.h>
#include <hip/hip_bf16.h>
#include <stdint.h>

#define N_NODES 50000
#define N_EDGES 800000
#define NH 8
#define VD 320

typedef float f32x4 __attribute__((ext_vector_type(4)));

// ---- K0: zero degree counts + global cursor ----
__global__ void k_init(unsigned* __restrict__ cnt, unsigned* __restrict__ total) {
    int i = blockIdx.x * blockDim.x + threadIdx.x;
    int stride = gridDim.x * blockDim.x;
    for (int j = i; j < N_NODES; j += stride) cnt[j] = 0u;
    if (i == 0) *total = 0u;
}

// ---- K1: degree histogram ----
__global__ __launch_bounds__(256) void k_hist(
        const int* __restrict__ dst, unsigned* __restrict__ cnt) {
    int e = blockIdx.x * 256 + threadIdx.x;
    if (e >= N_EDGES) return;
    atomicAdd(&cnt[dst[e]], 1u);
}

// ---- K2: unordered CSR range allocation (wave-scan + one atomic per wave) ----
__global__ __launch_bounds__(256) void k_ranges(
        const unsigned* __restrict__ cnt, unsigned* __restrict__ rowstart,
        unsigned* __restrict__ cursor, unsigned* __restrict__ total) {
    int i = blockIdx.x * 256 + threadIdx.x;
    int lane = threadIdx.x & 63;
    unsigned c = (i < N_NODES) ? cnt[i] : 0u;
    unsigned incl = c;
    #pragma unroll
    for (int off = 1; off < 64; off <<= 1) {
        unsigned v = __shfl_up(incl, off, 64);
        if (lane >= off) incl += v;
    }
    unsigned wave_total = __shfl(incl, 63, 64);
    unsigned base = 0;
    if (lane == 63) base = atomicAdd(total, wave_total);
    base = __shfl(base, 63, 64);
    if (i < N_NODES) {
        unsigned st = base + incl - c;
        rowstart[i] = st;
        cursor[i] = st;
    }
}

// ---- K3: scatter edge id + all-8-head exp(cutoff*ew) into CSR slots ----
// Moves the exp AND the random ew access out of the gather inner loop:
// gather then reads eid/pexpf sequentially (and L3-hot, freshly written),
// leaving value rows as the ONLY random DRAM traffic.
// softmax is shift-invariant and |cutoff*ew| <= ~6, so no max-subtraction
// (validated R1-R5: absmax 0.0078 << 0.078 threshold).
__global__ __launch_bounds__(256) void k_scatter(
        const int* __restrict__ dst, const float* __restrict__ cutoff,
        const float* __restrict__ ew, unsigned* __restrict__ cursor,
        unsigned* __restrict__ eidArr, float* __restrict__ pexpf) {
    int e = blockIdx.x * 256 + threadIdx.x;
    if (e >= N_EDGES) return;
    float cu = cutoff[e];
    const f32x4* ewv = reinterpret_cast<const f32x4*>(ew + (size_t)e * NH);
    f32x4 w0 = ewv[0], w1 = ewv[1];
    f32x4 p0, p1;
    p0.x = __expf(cu * w0.x); p0.y = __expf(cu * w0.y);
    p0.z = __expf(cu * w0.z); p0.w = __expf(cu * w0.w);
    p1.x = __expf(cu * w1.x); p1.y = __expf(cu * w1.y);
    p1.z = __expf(cu * w1.z); p1.w = __expf(cu * w1.w);
    unsigned pos = atomicAdd(&cursor[dst[e]], 1u);
    eidArr[pos] = (unsigned)e;
    f32x4* pv = reinterpret_cast<f32x4*>(pexpf + (size_t)pos * NH);
    pv[0] = p0; pv[1] = p1;
}

// ---- K4: wave-per-node gather ----
// One wave64 owns a node. Lane l handles cols [4l,4l+3]; lanes 0-15 additionally
// cols [256+4l..]. Edge-id chunk (64) register-cached, broadcast via shfl.
// Attention numerators read per-lane from pexpf: sequential, 1-line-coalesced,
// L1/L3-hot. Denominator accumulated inline; scaled once at the end.
__global__ __launch_bounds__(256) void k_gather(
        const float* __restrict__ pexpf, const float* __restrict__ value,
        const unsigned* __restrict__ rowstart, const unsigned* __restrict__ cnt,
        const unsigned* __restrict__ eidArr, float* __restrict__ out) {
    int lane = threadIdx.x & 63;
    int wslot = blockIdx.x * 4 + (threadIdx.x >> 6);
    int nslots = gridDim.x * 4;
    int c = lane * 4;
    int h = (c < 128) ? (c >> 4) : ((c - 128) / 24);
    int c2 = 256 + c;                 // secondary cols, lanes 0-15 only
    int h2 = (c2 - 128) / 24;
    bool sec = lane < 16;
    for (int n = wslot; n < N_NODES; n += nslots) {
        unsigned k0 = rowstart[n];
        unsigned deg = cnt[n];
        f32x4 acc = {0.f, 0.f, 0.f, 0.f}, acc2 = {0.f, 0.f, 0.f, 0.f};
        float se = 0.f, se2 = 0.f;
        for (unsigned base = 0; base < deg; base += 64) {
            unsigned m = deg - base; if (m > 64u) m = 64u;
            unsigned pe = 0u;
            if (lane < (int)m) pe = eidArr[k0 + base + lane];
            const float* pb = pexpf + (size_t)(k0 + base) * NH;
            #pragma unroll 2
            for (unsigned j = 0; j < m; ++j) {
                unsigned e = (unsigned)__shfl((int)pe, (int)j, 64);
                float a = pb[j * NH + h];           // L1-hot sequential
                const float* vrow = value + (size_t)e * VD;
                f32x4 v = __builtin_nontemporal_load(
                    reinterpret_cast<const f32x4*>(vrow + c));
                se += a;
                acc.x += a * v.x; acc.y += a * v.y;
                acc.z += a * v.z; acc.w += a * v.w;
                if (sec) {
                    float a2 = pb[j * NH + h2];
                    f32x4 v2 = __builtin_nontemporal_load(
                        reinterpret_cast<const f32x4*>(vrow + c2));
                    se2 += a2;
                    acc2.x += a2 * v2.x; acc2.y += a2 * v2.y;
                    acc2.z += a2 * v2.z; acc2.w += a2 * v2.w;
                }
            }
        }
        float sc = (deg > 0) ? 1.0f / se : 0.0f;
        f32x4 r; r.x = acc.x * sc; r.y = acc.y * sc;
        r.z = acc.z * sc; r.w = acc.w * sc;
        __builtin_nontemporal_store(r,
            reinterpret_cast<f32x4*>(out + (size_t)n * VD + c));
        if (sec) {
            float sc2 = (deg > 0) ? 1.0f / se2 : 0.0f;
            f32x4 r2; r2.x = acc2.x * sc2; r2.y = acc2.y * sc2;
            r2.z = acc2.z * sc2; r2.w = acc2.w * sc2;
            __builtin_nontemporal_store(r2,
                reinterpret_cast<f32x4*>(out + (size_t)n * VD + c2));
        }
    }
}

extern "C" void kernel_launch(void* const* d_in, const int* in_sizes, int n_in,
                              void* d_out, int out_size, void* d_ws, size_t ws_size,
                              hipStream_t stream) {
    const float* value  = (const float*)d_in[0];
    const float* ew     = (const float*)d_in[1];
    const float* cutoff = (const float*)d_in[2];
    const int*   eidx   = (const int*)d_in[3];
    const int*   dst    = eidx + N_EDGES;  // edge_index[1]
    float* out = (float*)d_out;

    char* ws = (char*)d_ws;
    float*    pexpf    = (float*)ws;    ws += (size_t)N_EDGES * NH * 4;   // 25.6 MB, 32B-aligned
    unsigned* eidArr   = (unsigned*)ws; ws += (size_t)N_EDGES * 4;        // 3.2 MB
    unsigned* cnt      = (unsigned*)ws; ws += (size_t)((N_NODES + 3) & ~3) * 4;
    unsigned* rowstart = (unsigned*)ws; ws += (size_t)((N_NODES + 3) & ~3) * 4;
    unsigned* cursor   = (unsigned*)ws; ws += (size_t)((N_NODES + 3) & ~3) * 4;
    unsigned* total    = (unsigned*)ws; ws += 16;

    const int gE = (N_EDGES + 255) / 256;   // 3125
    const int gN = (N_NODES + 255) / 256;   // 196

    k_init<<<196, 256, 0, stream>>>(cnt, total);
    k_hist<<<gE, 256, 0, stream>>>(dst, cnt);
    k_ranges<<<gN, 256, 0, stream>>>(cnt, rowstart, cursor, total);
    k_scatter<<<gE, 256, 0, stream>>>(dst, cutoff, ew, cursor, eidArr, pexpf);
    k_gather<<<2048, 256, 0, stream>>>(pexpf, value, rowstart, cnt, eidArr, out);
}